// Round 1
// baseline (4415.813 us; speedup 1.0000x reference)
//
#include <hip/hip_runtime.h>

#define HDIM 256
#define TDIM 256
#define VOUT 10
#define BC   8     // batch rows per block

__device__ __forceinline__ float fast_tanh(float a) {
    // tanh(a) = 1 - 2/(exp(2a)+1), clamped to avoid inf
    float t = fminf(fmaxf(a, -15.0f), 15.0f);
    float e = __expf(2.0f * t);
    return 1.0f - 2.0f * __builtin_amdgcn_rcpf(e + 1.0f);
}

__global__ __launch_bounds__(256, 1) void rnn_fwd_f32(
    const float* __restrict__ x,    // [B, T]   (last dim 1 squeezed)
    const float* __restrict__ We,   // [H]      (W_e is [1,H])
    const float* __restrict__ be,   // [H]
    const float* __restrict__ Wh,   // [H, H]   (in, out)
    const float* __restrict__ bh,   // [H]
    const float* __restrict__ Wo,   // [H, V]
    const float* __restrict__ bo,   // [V]
    float* __restrict__ out)        // [B, V]
{
    __shared__ float v_lds[2][BC][HDIM];   // 16 KB: inp_t + h (double buffered)
    __shared__ float x_lds[BC][TDIM];      // 8 KB: this block's x rows
    __shared__ float h_lds[BC][HDIM];      // 8 KB: final h

    const int j  = threadIdx.x;            // output column owned by this thread
    const int r0 = blockIdx.x * BC;        // first batch row of this block

    // stage x rows (coalesced: consecutive tid -> consecutive t)
    for (int k = j; k < BC * TDIM; k += 256) {
        int r = k >> 8, t = k & 255;
        x_lds[r][t] = x[(r0 + r) * TDIM + t];
    }

    const float We_j = We[j];
    const float be_j = be[j];
    const float bh_j = bh[j];

    __syncthreads();

    // v(0) = tanh(x[:,0]*We + be)  (h0 = 0)
    #pragma unroll
    for (int r = 0; r < BC; ++r)
        v_lds[0][r][j] = fast_tanh(x_lds[r][0] * We_j + be_j);
    __syncthreads();

    int cur = 0;
    for (int t = 0; t < TDIM; ++t) {
        float acc[BC];
        #pragma unroll
        for (int r = 0; r < BC; ++r) acc[r] = bh_j;

        const float* __restrict__ wcol = Wh + j;
        #pragma unroll 4
        for (int i4 = 0; i4 < HDIM / 4; ++i4) {
            // column j of W_h, 4 consecutive i's (coalesced across threads)
            float w0 = wcol[(i4 * 4 + 0) * HDIM];
            float w1 = wcol[(i4 * 4 + 1) * HDIM];
            float w2 = wcol[(i4 * 4 + 2) * HDIM];
            float w3 = wcol[(i4 * 4 + 3) * HDIM];
            #pragma unroll
            for (int r = 0; r < BC; ++r) {
                // wave-uniform address -> LDS broadcast, conflict-free
                const float4 v = *(const float4*)&v_lds[cur][r][i4 * 4];
                acc[r] = fmaf(v.x, w0, acc[r]);
                acc[r] = fmaf(v.y, w1, acc[r]);
                acc[r] = fmaf(v.z, w2, acc[r]);
                acc[r] = fmaf(v.w, w3, acc[r]);
            }
        }

        if (t + 1 < TDIM) {
            #pragma unroll
            for (int r = 0; r < BC; ++r) {
                float h   = fast_tanh(acc[r]);
                float inp = fast_tanh(x_lds[r][t + 1] * We_j + be_j);
                v_lds[cur ^ 1][r][j] = inp + h;   // v(t+1)
            }
        } else {
            #pragma unroll
            for (int r = 0; r < BC; ++r)
                h_lds[r][j] = fast_tanh(acc[r]); // h_final
        }
        cur ^= 1;
        __syncthreads();
    }

    // epilogue: out[r][v] = bo[v] + sum_i h[r][i] * Wo[i*V+v]
    if (j < BC * VOUT) {
        int r = j / VOUT, v = j - r * VOUT;
        float s = bo[v];
        #pragma unroll 8
        for (int i = 0; i < HDIM; ++i)
            s = fmaf(h_lds[r][i], Wo[i * VOUT + v], s);
        out[(r0 + r) * VOUT + v] = s;
    }
}

extern "C" void kernel_launch(void* const* d_in, const int* in_sizes, int n_in,
                              void* d_out, int out_size, void* d_ws, size_t ws_size,
                              hipStream_t stream) {
    const float* x  = (const float*)d_in[0];
    const float* We = (const float*)d_in[1];
    const float* be = (const float*)d_in[2];
    const float* Wh = (const float*)d_in[3];
    const float* bh = (const float*)d_in[4];
    const float* Wo = (const float*)d_in[5];
    const float* bo = (const float*)d_in[6];
    float* out = (float*)d_out;

    const int B = in_sizes[0] / TDIM;      // 2048
    const int nblocks = B / BC;            // 256

    rnn_fwd_f32<<<nblocks, 256, 0, stream>>>(x, We, be, Wh, bh, Wo, bo, out);
}

// Round 2
// 3220.771 us; speedup vs baseline: 1.3710x; 1.3710x over previous
//
#include <hip/hip_runtime.h>

#define HDIM 256
#define TDIM 256
#define VOUT 10
#define BC   8     // batch rows per block

__device__ __forceinline__ float fast_tanh(float a) {
    // tanh(a) = 1 - 2/(exp(2a)+1), clamped to avoid inf
    float t = fminf(fmaxf(a, -15.0f), 15.0f);
    float e = __expf(2.0f * t);
    return 1.0f - 2.0f * __builtin_amdgcn_rcpf(e + 1.0f);
}

// Thread t: iq = t&3 (i-slice, round-robin float4 chunks), jg = t>>2 (4 columns).
// W_h slice lives in 256 VGPRs; v broadcast from LDS (contiguous 64B per read).
__global__ __launch_bounds__(256, 1) void rnn_fwd_f32_regw(
    const float* __restrict__ x,    // [B, T]
    const float* __restrict__ We,   // [H]
    const float* __restrict__ be,   // [H]
    const float* __restrict__ Wh,   // [H, H] (in, out)
    const float* __restrict__ bh,   // [H]
    const float* __restrict__ Wo,   // [H, V]
    const float* __restrict__ bo,   // [V]
    float* __restrict__ out)        // [B, V]
{
    __shared__ float v_lds[2][BC * HDIM];  // 16 KB (double buffered)
    __shared__ float x_lds[BC][TDIM];      // 8 KB
    __shared__ float h_lds[BC][HDIM];      // 8 KB

    const int tid = threadIdx.x;
    const int iq  = tid & 3;        // i-slice within lane-quad
    const int jg  = tid >> 2;       // column group
    const int jc0 = jg * 4;         // first owned column
    const int r0  = blockIdx.x * BC;

    // stage x rows (coalesced)
    for (int k = tid; k < BC * TDIM; k += 256) {
        int r = k >> 8, t = k & 255;
        x_lds[r][t] = x[(r0 + r) * TDIM + t];
    }

    // W slice -> registers: w[s][u][c] = Wh[i][jc0+c], i = (s*4+iq)*4+u
    // (per instr: 4 iq-clusters of 16 lanes x 16B contiguous -> coalesced)
    float w[16][4][4];
    #pragma unroll
    for (int s = 0; s < 16; ++s) {
        #pragma unroll
        for (int u = 0; u < 4; ++u) {
            const float4 t4 = *(const float4*)&Wh[((s * 4 + iq) * 4 + u) * HDIM + jc0];
            w[s][u][0] = t4.x; w[s][u][1] = t4.y; w[s][u][2] = t4.z; w[s][u][3] = t4.w;
        }
    }

    const float4 bh4 = *(const float4*)&bh[jc0];
    const float4 We4 = *(const float4*)&We[jc0];
    const float4 be4 = *(const float4*)&be[jc0];

    __syncthreads();

    // v(0) = tanh(x[:,0]*We + be); lane iq writes rows {iq*2, iq*2+1}
    #pragma unroll
    for (int rr = 0; rr < 2; ++rr) {
        const int r = iq * 2 + rr;
        const float xv = x_lds[r][0];
        float4 o;
        o.x = fast_tanh(xv * We4.x + be4.x);
        o.y = fast_tanh(xv * We4.y + be4.y);
        o.z = fast_tanh(xv * We4.z + be4.z);
        o.w = fast_tanh(xv * We4.w + be4.w);
        *(float4*)&v_lds[0][r * HDIM + jc0] = o;
    }
    __syncthreads();

    int cur = 0;
    #pragma unroll 1
    for (int t = 0; t < TDIM; ++t) {
        float acc[BC][4];
        #pragma unroll
        for (int r = 0; r < BC; ++r)
            #pragma unroll
            for (int c = 0; c < 4; ++c) acc[r][c] = 0.0f;

        // i = s*16 + iq*4 + u  <-> matches w[s][u][c] load order
        const float* vb = &v_lds[cur][0] + iq * 4;
        #pragma unroll
        for (int s = 0; s < 16; ++s) {
            #pragma unroll
            for (int r = 0; r < BC; ++r) {
                const float4 v4 = *(const float4*)&vb[r * HDIM + s * 16];
                #pragma unroll
                for (int c = 0; c < 4; ++c) {
                    acc[r][c] = fmaf(v4.x, w[s][0][c], acc[r][c]);
                    acc[r][c] = fmaf(v4.y, w[s][1][c], acc[r][c]);
                    acc[r][c] = fmaf(v4.z, w[s][2][c], acc[r][c]);
                    acc[r][c] = fmaf(v4.w, w[s][3][c], acc[r][c]);
                }
            }
        }

        // Reduce over the lane-quad (iq dim) while narrowing rows so each
        // lane ends with rows {iq*2, iq*2+1} in compile-time slots.
        float red[4][4];   // rows base2+0..3, base2 = (iq&2)?4:0
        #pragma unroll
        for (int r = 0; r < 4; ++r)
            #pragma unroll
            for (int c = 0; c < 4; ++c) {
                const float send = (iq & 2) ? acc[r][c] : acc[r + 4][c];
                const float keep = (iq & 2) ? acc[r + 4][c] : acc[r][c];
                red[r][c] = keep + __shfl_xor(send, 2);
            }
        float fin[2][4];   // rows iq*2 + {0,1}
        #pragma unroll
        for (int rr = 0; rr < 2; ++rr)
            #pragma unroll
            for (int c = 0; c < 4; ++c) {
                const float send = (iq & 1) ? red[rr][c] : red[rr + 2][c];
                const float keep = (iq & 1) ? red[rr + 2][c] : red[rr][c];
                fin[rr][c] = keep + __shfl_xor(send, 1);
            }

        if (t + 1 < TDIM) {
            float* vnb = &v_lds[cur ^ 1][0];
            #pragma unroll
            for (int rr = 0; rr < 2; ++rr) {
                const int r = iq * 2 + rr;
                const float xv = x_lds[r][t + 1];
                float4 o;
                o.x = fast_tanh(fin[rr][0] + bh4.x) + fast_tanh(xv * We4.x + be4.x);
                o.y = fast_tanh(fin[rr][1] + bh4.y) + fast_tanh(xv * We4.y + be4.y);
                o.z = fast_tanh(fin[rr][2] + bh4.z) + fast_tanh(xv * We4.z + be4.z);
                o.w = fast_tanh(fin[rr][3] + bh4.w) + fast_tanh(xv * We4.w + be4.w);
                *(float4*)&vnb[r * HDIM + jc0] = o;
            }
        } else {
            #pragma unroll
            for (int rr = 0; rr < 2; ++rr) {
                const int r = iq * 2 + rr;
                float4 o;
                o.x = fast_tanh(fin[rr][0] + bh4.x);
                o.y = fast_tanh(fin[rr][1] + bh4.y);
                o.z = fast_tanh(fin[rr][2] + bh4.z);
                o.w = fast_tanh(fin[rr][3] + bh4.w);
                *(float4*)&h_lds[r][jc0] = o;
            }
        }
        cur ^= 1;
        __syncthreads();
    }

    // epilogue: out[r][v] = bo[v] + sum_i h[r][i] * Wo[i*V+v]
    if (tid < BC * VOUT) {
        const int r = tid / VOUT, v = tid - r * VOUT;
        float s = bo[v];
        #pragma unroll 8
        for (int i = 0; i < HDIM; ++i)
            s = fmaf(h_lds[r][i], Wo[i * VOUT + v], s);
        out[(r0 + r) * VOUT + v] = s;
    }
}

extern "C" void kernel_launch(void* const* d_in, const int* in_sizes, int n_in,
                              void* d_out, int out_size, void* d_ws, size_t ws_size,
                              hipStream_t stream) {
    const float* x  = (const float*)d_in[0];
    const float* We = (const float*)d_in[1];
    const float* be = (const float*)d_in[2];
    const float* Wh = (const float*)d_in[3];
    const float* bh = (const float*)d_in[4];
    const float* Wo = (const float*)d_in[5];
    const float* bo = (const float*)d_in[6];
    float* out = (float*)d_out;

    const int B = in_sizes[0] / TDIM;      // 2048
    const int nblocks = B / BC;            // 256

    rnn_fwd_f32_regw<<<nblocks, 256, 0, stream>>>(x, We, be, Wh, bh, Wo, bo, out);
}

// Round 3
// 263.721 us; speedup vs baseline: 16.7443x; 12.2128x over previous
//
#include <hip/hip_runtime.h>

#define HDIM 256
#define TDIM 256
#define VOUT 10
#define BC   16    // batch rows per block (MFMA N dim)

typedef _Float16 f16x8 __attribute__((ext_vector_type(8)));
typedef float    f32x4 __attribute__((ext_vector_type(4)));

__device__ __forceinline__ float fast_tanh(float a) {
    // tanh(a) = 1 - 2/(exp(2a)+1). |a| <= ~32 here -> e^64 finite, no clamp needed.
    float e = __expf(2.0f * a);
    return 1.0f - 2.0f * __builtin_amdgcn_rcpf(e + 1.0f);
}

// Swapped-operand MFMA recurrence: per step compute D = Wh^T (256x256) x v^T (256x16).
// Wave w owns h-cols [64w, 64w+64) = 4 M-tiles. Lane l: n = l&15 (batch row / D col),
// g = l>>4. D layout (m89): hcol = 64w+16mt+4g+reg, batch = n.
// v stored in LDS as [n][hcol] f16, 16B chunks XOR-swizzled by (n&7).
__global__ __launch_bounds__(256, 1) void rnn_fwd_mfma(
    const float* __restrict__ x,    // [B, T]
    const float* __restrict__ We,   // [H]
    const float* __restrict__ be,   // [H]
    const float* __restrict__ Wh,   // [H, H] (in, out)
    const float* __restrict__ bh,   // [H]
    const float* __restrict__ Wo,   // [H, V]
    const float* __restrict__ bo,   // [V]
    float* __restrict__ out)        // [B, V]
{
    __shared__ __align__(16) char vraw[2][BC * HDIM * 2];  // 2 x 8 KB f16, swizzled
    __shared__ float x_lds[BC][TDIM + 2];                  // stride 258: conflict-free col reads
    __shared__ float h_fin[BC][HDIM + 1];

    const int tid = threadIdx.x;
    const int l   = tid & 63;
    const int w   = tid >> 6;       // wave id -> h-cols [64w, 64w+64)
    const int n   = l & 15;         // batch row
    const int g   = l >> 4;         // lane group
    const int s   = n & 7;          // LDS swizzle key
    const int r0  = blockIdx.x * BC;

    // ---- stage x (coalesced) ----
    for (int k = tid; k < BC * TDIM; k += 256) {
        int r = k >> 8, t = k & 255;
        x_lds[r][t] = x[(r0 + r) * TDIM + t];
    }

    // ---- W_h -> register fragments (one-time; zero per-step W traffic) ----
    // A-frag (16x32 tile at (mt,kt)): lane holds row=n (hcol), k = kt*32 + g*8 + e
    // wfrag[mt][kt][e] = Wh^T[64w+16mt+n][kt*32+g*8+e] = Wh[kt*32+g*8+e][64w+16mt+n]
    f16x8 wfrag[4][8];
    #pragma unroll
    for (int mt = 0; mt < 4; ++mt) {
        const int col = 64 * w + 16 * mt + n;
        #pragma unroll
        for (int kt = 0; kt < 8; ++kt) {
            #pragma unroll
            for (int e = 0; e < 8; ++e)
                wfrag[mt][kt][e] = (_Float16)Wh[(kt * 32 + g * 8 + e) * HDIM + col];
        }
    }

    // ---- per-lane We/be/bh for owned hcols (hcol = 64w + 16mt + 4g + reg) ----
    float Wef[4][4], bef[4][4], bhf[4][4];
    #pragma unroll
    for (int mt = 0; mt < 4; ++mt) {
        const int hc = 64 * w + 16 * mt + 4 * g;
        #pragma unroll
        for (int rg = 0; rg < 4; ++rg) {
            Wef[mt][rg] = We[hc + rg];
            bef[mt][rg] = be[hc + rg];
            bhf[mt][rg] = bh[hc + rg];
        }
    }

    // ---- swizzled LDS byte addresses within a vbuf plane ----
    // read B-frag kt: v[n][kt*32 + g*8 .. +7] -> chunk (4kt+g)^s
    //   addr = n*512 + (kt^(s>>2))*64 + ((g^(s&3))*16)
    const int base_r = n * 512 + ((g ^ (s & 3)) << 4);
    const int kthi   = s >> 2;
    // write (per mt): 4 f16 at hcol0 = 64w+16mt+4g -> chunk 8w+2mt+(g>>1), half 8*(g&1)
    int addr_w[4];
    #pragma unroll
    for (int mt = 0; mt < 4; ++mt)
        addr_w[mt] = n * 512 + (((8 * w + 2 * mt + (g >> 1)) ^ s) << 4) + 8 * (g & 1);

    __syncthreads();

    // ---- v(0) = tanh(x[:,0]*We + be)  (h0 = 0) ----
    {
        const float xv = x_lds[n][0];
        #pragma unroll
        for (int mt = 0; mt < 4; ++mt) {
            union { _Float16 h[4]; uint2 u2; } pk;
            #pragma unroll
            for (int rg = 0; rg < 4; ++rg)
                pk.h[rg] = (_Float16)fast_tanh(xv * Wef[mt][rg] + bef[mt][rg]);
            *(uint2*)(&vraw[0][0] + addr_w[mt]) = pk.u2;
        }
    }
    __syncthreads();

    int cur = 0;
    #pragma unroll 1
    for (int t = 0; t < TDIM; ++t) {
        const char* vr = &vraw[cur][0];

        // independent of MFMA: next-step input tanh (hides under lgkm/MFMA waits)
        float inpv[4][4];
        const bool last = (t + 1 == TDIM);
        if (!last) {
            const float xv = x_lds[n][t + 1];
            #pragma unroll
            for (int mt = 0; mt < 4; ++mt)
                #pragma unroll
                for (int rg = 0; rg < 4; ++rg)
                    inpv[mt][rg] = fast_tanh(xv * Wef[mt][rg] + bef[mt][rg]);
        }

        f16x8 bfrag[8];
        #pragma unroll
        for (int kt = 0; kt < 8; ++kt)
            bfrag[kt] = *(const f16x8*)(vr + base_r + ((kt ^ kthi) << 6));

        f32x4 acc[4];
        #pragma unroll
        for (int mt = 0; mt < 4; ++mt) {
            acc[mt][0] = bhf[mt][0]; acc[mt][1] = bhf[mt][1];
            acc[mt][2] = bhf[mt][2]; acc[mt][3] = bhf[mt][3];
        }

        #pragma unroll
        for (int kt = 0; kt < 8; ++kt)
            #pragma unroll
            for (int mt = 0; mt < 4; ++mt)
                acc[mt] = __builtin_amdgcn_mfma_f32_16x16x32_f16(
                    wfrag[mt][kt], bfrag[kt], acc[mt], 0, 0, 0);

        if (!last) {
            char* vw = &vraw[cur ^ 1][0];
            #pragma unroll
            for (int mt = 0; mt < 4; ++mt) {
                union { _Float16 h[4]; uint2 u2; } pk;
                #pragma unroll
                for (int rg = 0; rg < 4; ++rg)
                    pk.h[rg] = (_Float16)(fast_tanh(acc[mt][rg]) + inpv[mt][rg]);
                *(uint2*)(vw + addr_w[mt]) = pk.u2;
            }
        } else {
            #pragma unroll
            for (int mt = 0; mt < 4; ++mt) {
                const int hc = 64 * w + 16 * mt + 4 * g;
                #pragma unroll
                for (int rg = 0; rg < 4; ++rg)
                    h_fin[n][hc + rg] = fast_tanh(acc[mt][rg]);
            }
        }
        cur ^= 1;
        __syncthreads();
    }

    // ---- epilogue: out[r][v] = bo[v] + sum_i h[r][i] * Wo[i*V+v] ----
    if (tid < BC * VOUT) {
        const int r = tid / VOUT, vc = tid - r * VOUT;
        float sacc = bo[vc];
        #pragma unroll 8
        for (int i = 0; i < HDIM; ++i)
            sacc = fmaf(h_fin[r][i], Wo[i * VOUT + vc], sacc);
        out[(r0 + r) * VOUT + vc] = sacc;
    }
}

extern "C" void kernel_launch(void* const* d_in, const int* in_sizes, int n_in,
                              void* d_out, int out_size, void* d_ws, size_t ws_size,
                              hipStream_t stream) {
    const float* x  = (const float*)d_in[0];
    const float* We = (const float*)d_in[1];
    const float* be = (const float*)d_in[2];
    const float* Wh = (const float*)d_in[3];
    const float* bh = (const float*)d_in[4];
    const float* Wo = (const float*)d_in[5];
    const float* bo = (const float*)d_in[6];
    float* out = (float*)d_out;

    const int B = in_sizes[0] / TDIM;      // 2048
    const int nblocks = B / BC;            // 128

    rnn_fwd_mfma<<<nblocks, 256, 0, stream>>>(x, We, be, Wh, bh, Wo, bo, out);
}

// Round 4
// 239.950 us; speedup vs baseline: 18.4031x; 1.0991x over previous
//
#include <hip/hip_runtime.h>

#define HDIM 256
#define TDIM 256
#define VOUT 10
#define BC   16    // batch rows per block (MFMA N dim)
#define NW   8     // waves per block -> 2 waves/SIMD

typedef _Float16 f16x8 __attribute__((ext_vector_type(8)));
typedef float    f32x4 __attribute__((ext_vector_type(4)));

__device__ __forceinline__ float fast_tanh(float a) {
    // tanh(a) = 1 - 2/(exp(2a)+1). |a| bounded (~32) -> no clamp needed.
    float e = __expf(2.0f * a);
    return 1.0f - 2.0f * __builtin_amdgcn_rcpf(e + 1.0f);
}

// Swapped-operand MFMA recurrence: per step D = Wh^T (256x256) x v^T (256x16).
// Wave w owns h-cols [32w, 32w+32) = 2 M-tiles. Lane l: n = l&15 (batch row),
// g = l>>4. D layout (m89): hcol = 32w+16mt+4g+rg, batch = n.
// v in LDS as [n][hcol] f16, 16B chunks XOR-swizzled: chunk' = chunk ^ (n&7).
__global__ __launch_bounds__(512, 1) void rnn_fwd_mfma8(
    const float* __restrict__ x,    // [B, T]
    const float* __restrict__ We,   // [H]
    const float* __restrict__ be,   // [H]
    const float* __restrict__ Wh,   // [H, H] (in, out)
    const float* __restrict__ bh,   // [H]
    const float* __restrict__ Wo,   // [H, V]
    const float* __restrict__ bo,   // [V]
    float* __restrict__ out)        // [B, V]
{
    __shared__ __align__(16) char vraw[2][BC * HDIM * 2];  // 2 x 8 KB f16, swizzled
    __shared__ float x_lds[BC][TDIM + 2];                  // stride 258
    __shared__ float h_fin[BC][HDIM + 1];

    const int tid = threadIdx.x;
    const int l   = tid & 63;
    const int w   = tid >> 6;       // wave id 0..7 -> h-cols [32w, 32w+32)
    const int n   = l & 15;         // batch row
    const int g   = l >> 4;         // lane group
    const int s   = n & 7;          // LDS swizzle key
    const int r0  = blockIdx.x * BC;

    // ---- stage x (coalesced) ----
    for (int k = tid; k < BC * TDIM; k += 512) {
        int r = k >> 8, t = k & 255;
        x_lds[r][t] = x[(r0 + r) * TDIM + t];
    }

    // ---- W_h -> register fragments (one-time) ----
    // wfrag[mt][kt][e] = Wh^T[32w+16mt+n][kt*32+g*8+e] = Wh[kt*32+g*8+e][32w+16mt+n]
    f16x8 wfrag[2][8];
    #pragma unroll
    for (int mt = 0; mt < 2; ++mt) {
        const int col = 32 * w + 16 * mt + n;
        #pragma unroll
        for (int kt = 0; kt < 8; ++kt) {
            #pragma unroll
            for (int e = 0; e < 8; ++e)
                wfrag[mt][kt][e] = (_Float16)Wh[(kt * 32 + g * 8 + e) * HDIM + col];
        }
    }

    // ---- per-lane We/be/bh for owned hcols (hcol = 32w + 16mt + 4g + rg) ----
    float Wef[2][4], bef[2][4], bhf[2][4];
    #pragma unroll
    for (int mt = 0; mt < 2; ++mt) {
        const int hc = 32 * w + 16 * mt + 4 * g;
        #pragma unroll
        for (int rg = 0; rg < 4; ++rg) {
            Wef[mt][rg] = We[hc + rg];
            bef[mt][rg] = be[hc + rg];
            bhf[mt][rg] = bh[hc + rg];
        }
    }

    // ---- swizzled LDS byte addresses (chunk' = chunk ^ s, chunk = 16B unit) ----
    // read kt: v[n][kt*32 + g*8 ..] -> chunk 4kt+g -> addr below
    const int base_r = n * 512 + ((g ^ (s & 3)) << 4);
    const int kthi   = s >> 2;
    // write mt: 4 f16 at hcol0 = 32w+16mt+4g -> chunk 4w+2mt+(g>>1), half 8*(g&1)
    int addr_w[2];
    #pragma unroll
    for (int mt = 0; mt < 2; ++mt)
        addr_w[mt] = n * 512 + (((4 * w + 2 * mt + (g >> 1)) ^ s) << 4) + 8 * (g & 1);

    __syncthreads();

    // ---- v(0) = tanh(x[:,0]*We + be)  (h0 = 0) ----
    {
        const float xv = x_lds[n][0];
        #pragma unroll
        for (int mt = 0; mt < 2; ++mt) {
            union { _Float16 h[4]; uint2 u2; } pk;
            #pragma unroll
            for (int rg = 0; rg < 4; ++rg)
                pk.h[rg] = (_Float16)fast_tanh(xv * Wef[mt][rg] + bef[mt][rg]);
            *(uint2*)(&vraw[0][0] + addr_w[mt]) = pk.u2;
        }
    }
    __syncthreads();

    int cur = 0;
    #pragma unroll 1
    for (int t = 0; t < TDIM; ++t) {
        const char* vr = &vraw[cur][0];
        const bool last = (t + 1 == TDIM);

        // start LDS reads first (lgkm in flight)...
        f16x8 bfrag[8];
        #pragma unroll
        for (int kt = 0; kt < 8; ++kt)
            bfrag[kt] = *(const f16x8*)(vr + base_r + ((kt ^ kthi) << 6));

        // ...independent inp-tanh fills the wait shadow
        float inpv[2][4];
        if (!last) {
            const float xv = x_lds[n][t + 1];
            #pragma unroll
            for (int mt = 0; mt < 2; ++mt)
                #pragma unroll
                for (int rg = 0; rg < 4; ++rg)
                    inpv[mt][rg] = fast_tanh(xv * Wef[mt][rg] + bef[mt][rg]);
        }

        f32x4 acc[2];
        #pragma unroll
        for (int mt = 0; mt < 2; ++mt) {
            acc[mt][0] = bhf[mt][0]; acc[mt][1] = bhf[mt][1];
            acc[mt][2] = bhf[mt][2]; acc[mt][3] = bhf[mt][3];
        }

        #pragma unroll
        for (int kt = 0; kt < 8; ++kt)
            #pragma unroll
            for (int mt = 0; mt < 2; ++mt)
                acc[mt] = __builtin_amdgcn_mfma_f32_16x16x32_f16(
                    wfrag[mt][kt], bfrag[kt], acc[mt], 0, 0, 0);

        if (!last) {
            char* vw = &vraw[cur ^ 1][0];
            #pragma unroll
            for (int mt = 0; mt < 2; ++mt) {
                union { _Float16 h[4]; uint2 u2; } pk;
                #pragma unroll
                for (int rg = 0; rg < 4; ++rg)
                    pk.h[rg] = (_Float16)(fast_tanh(acc[mt][rg]) + inpv[mt][rg]);
                *(uint2*)(vw + addr_w[mt]) = pk.u2;
            }
        } else {
            #pragma unroll
            for (int mt = 0; mt < 2; ++mt) {
                const int hc = 32 * w + 16 * mt + 4 * g;
                #pragma unroll
                for (int rg = 0; rg < 4; ++rg)
                    h_fin[n][hc + rg] = fast_tanh(acc[mt][rg]);
            }
        }
        cur ^= 1;
        __syncthreads();
    }

    // ---- epilogue: out[r][v] = bo[v] + sum_i h[r][i] * Wo[i*V+v] ----
    if (tid < BC * VOUT) {
        const int r = tid / VOUT, vc = tid - r * VOUT;
        float sacc = bo[vc];
        #pragma unroll 8
        for (int i = 0; i < HDIM; ++i)
            sacc = fmaf(h_fin[r][i], Wo[i * VOUT + vc], sacc);
        out[(r0 + r) * VOUT + vc] = sacc;
    }
}

extern "C" void kernel_launch(void* const* d_in, const int* in_sizes, int n_in,
                              void* d_out, int out_size, void* d_ws, size_t ws_size,
                              hipStream_t stream) {
    const float* x  = (const float*)d_in[0];
    const float* We = (const float*)d_in[1];
    const float* be = (const float*)d_in[2];
    const float* Wh = (const float*)d_in[3];
    const float* bh = (const float*)d_in[4];
    const float* Wo = (const float*)d_in[5];
    const float* bo = (const float*)d_in[6];
    float* out = (float*)d_out;

    const int B = in_sizes[0] / TDIM;      // 2048
    const int nblocks = B / BC;            // 128

    rnn_fwd_mfma8<<<nblocks, 512, 0, stream>>>(x, We, be, Wh, bh, Wo, bo, out);
}